// Round 9
// baseline (284.017 us; speedup 1.0000x reference)
//
#include <hip/hip_runtime.h>
#include <math.h>

#define T_IN 2048
#define TP   2051        // T+3 conv output length
#define F    256
#define H    384
#define TT   2080        // xpT row stride (t-dim padded: 65*32)
#define MT   65          // t-tiles of 32
#define NCS  260         // 8-t chunks (65*4)
#define NC3  257         // chunks with t < TP
#define WTS  (256 * 384)

__device__ __forceinline__ float logsig(float z) {
    return (z >= 0.0f) ? -log1pf(__expf(-z)) : z - log1pf(__expf(z));
}

// ================= P1: conv->xpT | W transpose -> Wt[k][b] | q,o | ticket zero =================
__global__ __launch_bounds__(256) void p1_prep(
    const float* __restrict__ x, const float* __restrict__ cw, const float* __restrict__ cb,
    const float* __restrict__ Wk, const float* __restrict__ Wi, const float* __restrict__ Wf,
    const float* __restrict__ Wq, const float* __restrict__ bq,
    const float* __restrict__ Wo, const float* __restrict__ bo,
    float* __restrict__ xpT, float* __restrict__ Wt,
    float* __restrict__ qv, float* __restrict__ ov, int* __restrict__ ticket) {
    int bx = blockIdx.x, tid = threadIdx.x;
    if (bx < 513) {                      // ---- conv: 4 t rows -> xpT scatter
        int t = bx * 4 + (tid >> 6);
        int f4 = tid & 63;
        if (t >= TP) return;
        float w4[4] = {cw[0], cw[1], cw[2], cw[3]};
        float bb = cb[0];
        float4 acc = {bb, bb, bb, bb};
        #pragma unroll
        for (int j = 0; j < 4; ++j) {
            int tt = t - 3 + j;
            if (tt >= 0 && tt < T_IN) {
                float4 xv = *(const float4*)&x[tt * 256 + f4 * 4];
                float wj = w4[j];
                acc.x = fmaf(wj, xv.x, acc.x);
                acc.y = fmaf(wj, xv.y, acc.y);
                acc.z = fmaf(wj, xv.z, acc.z);
                acc.w = fmaf(wj, xv.w, acc.w);
            }
        }
        int k0 = f4 * 4;
        xpT[(k0 + 0) * TT + t] = acc.x;
        xpT[(k0 + 1) * TT + t] = acc.y;
        xpT[(k0 + 2) * TT + t] = acc.z;
        xpT[(k0 + 3) * TT + t] = acc.w;
    } else if (bx < 519) {               // ---- q/o at t=2050 (xp row = cb + cw0*x[2047])
        int lane = tid & 63, wid = tid >> 6;
        float w0 = cw[0], bb = cb[0];
        float4 xr = *(const float4*)&x[2047 * 256 + lane * 4];
        float4 xv = {bb + w0 * xr.x, bb + w0 * xr.y, bb + w0 * xr.z, bb + w0 * xr.w};
        for (int r = 0; r < 16; ++r) {
            int row = (bx - 513) * 64 + wid * 16 + r;
            float4 q4 = *(const float4*)&Wq[row * 256 + lane * 4];
            float4 o4 = *(const float4*)&Wo[row * 256 + lane * 4];
            float aq = fmaf(xv.x, q4.x, fmaf(xv.y, q4.y, fmaf(xv.z, q4.z, xv.w * q4.w)));
            float ao = fmaf(xv.x, o4.x, fmaf(xv.y, o4.y, fmaf(xv.z, o4.z, xv.w * o4.w)));
            #pragma unroll
            for (int off = 32; off; off >>= 1) {
                aq += __shfl_down(aq, off, 64);
                ao += __shfl_down(ao, off, 64);
            }
            if (lane == 0) {
                qv[row] = aq + bq[row];
                ov[row] = 1.0f / (1.0f + __expf(-(ao + bo[row])));
            }
        }
    } else if (bx < 807) {               // ---- transpose W[b][k] -> Wt[j][k][b]
        __shared__ float tl[32][33];
        int tb = bx - 519;
        int j = tb / 96, rem = tb % 96;
        int k0 = (rem / 12) * 32, b0 = (rem % 12) * 32;
        const float* W = (j == 0) ? Wk : (j == 1) ? Wi : Wf;
        int c = tid & 31, r0 = tid >> 5;
        #pragma unroll
        for (int s = 0; s < 4; ++s) {
            int r = r0 + 8 * s;
            tl[r][c] = W[(b0 + r) * 256 + k0 + c];
        }
        __syncthreads();
        float* dst = Wt + j * WTS;
        #pragma unroll
        for (int s = 0; s < 4; ++s) {
            int rr = r0 + 8 * s;
            dst[(k0 + rr) * 384 + b0 + c] = tl[c][rr];
        }
    } else {                              // ---- zero ticket
        if (tid == 0) ticket[0] = 0;
    }
}

// ================= P2: GEMM M=2080, N=3x384, K=256 =================
// grid (65,9) x 256 thr. Block: 32t x 128 cols of mat j=by/3.
// Wave owns 8 contiguous t's -> A reads are wave-uniform (scalar path);
// B via LDS ds_read_b64 (2-way free). acc = 8 x float2 per thread.
__global__ __launch_bounds__(256) void p2_gemm(
    const float* __restrict__ xpT, const float* __restrict__ Wt,
    const float* __restrict__ bk, const float* __restrict__ bi, const float* __restrict__ bf,
    float* __restrict__ zk, float* __restrict__ ai, float* __restrict__ lf,
    float* __restrict__ cs) {
    __shared__ float blds[2][32][132];
    int tid = threadIdx.x;
    int lane = tid & 63;
    int wid = __builtin_amdgcn_readfirstlane(tid >> 6);
    int bx = blockIdx.x, by = blockIdx.y;
    int j = by / 3;
    int c0 = (by % 3) * 128;
    const float* Wtj = Wt + j * WTS + c0;
    int t0w = bx * 32 + wid * 8;
    const float* aP = xpT + t0w;          // wave-uniform base
    int kr = tid >> 3, c4 = tid & 7;
    const float* bsrc = Wtj + kr * 384 + c4 * 4;
    float4 breg[4];
    #pragma unroll
    for (int h = 0; h < 4; ++h) breg[h] = *(const float4*)(bsrc + h * 32);
    float2 a0v = {0.f, 0.f};
    float2 acc0 = a0v, acc1 = a0v, acc2 = a0v, acc3 = a0v;
    float2 acc4 = a0v, acc5 = a0v, acc6 = a0v, acc7 = a0v;

    for (int kc = 0; kc < 8; ++kc) {
        int buf = kc & 1;
        __syncthreads();
        #pragma unroll
        for (int h = 0; h < 4; ++h)
            *(float4*)&blds[buf][kr][c4 * 4 + h * 32] = breg[h];
        __syncthreads();
        if (kc < 7) {
            const float* nb = bsrc + (kc + 1) * 32 * 384;
            #pragma unroll
            for (int h = 0; h < 4; ++h) breg[h] = *(const float4*)(nb + h * 32);
        }
        const float* aK = aP + kc * 32 * TT;
        #pragma unroll
        for (int kk = 0; kk < 32; ++kk) {
            float4 aA = *(const float4*)(aK + kk * TT);      // uniform -> scalar path
            float4 aB = *(const float4*)(aK + kk * TT + 4);
            float2 bv = *(const float2*)&blds[buf][kk][2 * lane];
            acc0.x = fmaf(aA.x, bv.x, acc0.x); acc0.y = fmaf(aA.x, bv.y, acc0.y);
            acc1.x = fmaf(aA.y, bv.x, acc1.x); acc1.y = fmaf(aA.y, bv.y, acc1.y);
            acc2.x = fmaf(aA.z, bv.x, acc2.x); acc2.y = fmaf(aA.z, bv.y, acc2.y);
            acc3.x = fmaf(aA.w, bv.x, acc3.x); acc3.y = fmaf(aA.w, bv.y, acc3.y);
            acc4.x = fmaf(aB.x, bv.x, acc4.x); acc4.y = fmaf(aB.x, bv.y, acc4.y);
            acc5.x = fmaf(aB.y, bv.x, acc5.x); acc5.y = fmaf(aB.y, bv.y, acc5.y);
            acc6.x = fmaf(aB.z, bv.x, acc6.x); acc6.y = fmaf(aB.z, bv.y, acc6.y);
            acc7.x = fmaf(aB.w, bv.x, acc7.x); acc7.y = fmaf(aB.w, bv.y, acc7.y);
        }
    }
    // epilogue (block-uniform branch on j)
    int col = c0 + 2 * lane;
    float2 accs[8] = {acc0, acc1, acc2, acc3, acc4, acc5, acc6, acc7};
    if (j == 0) {
        float2 b2 = *(const float2*)&bk[col];
        const float sc = 0.05103103630798287f;  // 1/sqrt(384)
        #pragma unroll
        for (int u = 0; u < 8; ++u) {
            int t = t0w + u;
            if (t < TP) {
                float2 v = {(accs[u].x + b2.x) * sc, (accs[u].y + b2.y) * sc};
                *(float2*)&zk[t * H + col] = v;
            }
        }
    } else if (j == 1) {
        float2 b2 = *(const float2*)&bi[col];
        #pragma unroll
        for (int u = 0; u < 8; ++u) {
            int t = t0w + u;
            if (t < TP) {
                float2 v = {accs[u].x + b2.x, accs[u].y + b2.y};
                *(float2*)&ai[t * H + col] = v;
            }
        }
    } else {
        float2 b2 = *(const float2*)&bf[col];
        float2 lfs = {0.f, 0.f};
        #pragma unroll
        for (int u = 0; u < 8; ++u) {
            int t = t0w + u;
            if (t < TP) {
                float2 v = {logsig(accs[u].x + b2.x), logsig(accs[u].y + b2.y)};
                *(float2*)&lf[t * H + col] = v;
                lfs.x += v.x; lfs.y += v.y;
            }
        }
        *(float2*)&cs[(bx * 4 + wid) * H + col] = lfs;   // chunk = t0w/8
    }
}

// ================= P3: suffix-scan + w/g/z partials + ticket finalize =================
__global__ __launch_bounds__(384) void p3_tail(
    const float* __restrict__ xpT, const float* __restrict__ ai,
    const float* __restrict__ lf, const float* __restrict__ zk,
    const float* __restrict__ cs, const float* __restrict__ qv,
    const float* __restrict__ ov, const float* __restrict__ Wv,
    const float* __restrict__ bv,
    float* __restrict__ zp, float* __restrict__ Gc, int* __restrict__ ticket,
    float* __restrict__ out) {
    __shared__ float gtl[6][8];
    __shared__ float gts[8];
    __shared__ float zl[256];
    __shared__ float Gs;
    __shared__ int flag;
    int tid = threadIdx.x;
    int w = tid >> 6, lane = tid & 63;
    int c = blockIdx.x, ts = c * 8;

    float co0 = 0.f;
    #pragma unroll 4
    for (int cc = c + 1; cc < NCS; ++cc) co0 += cs[cc * H + tid];
    float qb = qv[tid];

    float aiv[8], lfv[8], zkv[8];
    #pragma unroll
    for (int u = 0; u < 8; ++u) {
        if (ts + u < TP) {
            int idx = (ts + u) * H + tid;
            aiv[u] = ai[idx]; lfv[u] = lf[idx]; zkv[u] = zk[idx];
        } else {
            aiv[u] = -1e30f; lfv[u] = 0.f; zkv[u] = 0.f;
        }
    }
    float S = 0.f;
    #pragma unroll
    for (int u = 7; u >= 0; --u) {
        float wv = __expf(aiv[u] + co0 + S) * zkv[u] * qb;
        S += lfv[u];
        float s = wv;
        s += __shfl_xor(s, 1, 64);
        s += __shfl_xor(s, 2, 64);
        s += __shfl_xor(s, 4, 64);
        s += __shfl_xor(s, 8, 64);
        s += __shfl_xor(s, 16, 64);
        s += __shfl_xor(s, 32, 64);
        if (lane == 0) gtl[w][u] = s;
    }
    __syncthreads();
    if (tid < 8) {
        float g = gtl[0][tid] + gtl[1][tid] + gtl[2][tid]
                + gtl[3][tid] + gtl[4][tid] + gtl[5][tid];
        gts[tid] = g;
    }
    __syncthreads();
    if (tid < 256) {
        float4 xa = *(const float4*)&xpT[tid * TT + ts];
        float4 xb = *(const float4*)&xpT[tid * TT + ts + 4];
        float z = gts[0] * xa.x;
        z = fmaf(gts[1], xa.y, z);
        z = fmaf(gts[2], xa.z, z);
        z = fmaf(gts[3], xa.w, z);
        z = fmaf(gts[4], xb.x, z);
        z = fmaf(gts[5], xb.y, z);
        z = fmaf(gts[6], xb.z, z);
        z = fmaf(gts[7], xb.w, z);
        zp[c * 256 + tid] = z;
    }
    if (tid == 0) {
        float g = 0.f;
        #pragma unroll
        for (int u = 0; u < 8; ++u) g += gts[u];
        Gc[c] = g;
    }
    __threadfence();
    __syncthreads();
    if (tid == 0) {
        int old = atomicAdd(ticket, 1);
        flag = (old == NC3 - 1) ? 1 : 0;
    }
    __syncthreads();
    if (!flag) return;

    // ---- last block: reduce partials, final GEMV
    __threadfence();
    if (tid < 256) {
        float zsum = 0.f;
        #pragma unroll 4
        for (int cc = 0; cc < NC3; ++cc) zsum += zp[cc * 256 + tid];
        zl[tid] = zsum;
    } else if (tid < 320) {
        float g = 0.f;
        for (int cc = lane; cc < NC3; cc += 64) g += Gc[cc];
        #pragma unroll
        for (int off = 32; off; off >>= 1) g += __shfl_down(g, off, 64);
        if (lane == 0) Gs = g;
    }
    __syncthreads();
    float G = Gs;
    float den = fmaxf(fabsf(G), 1.0f);
    for (int r = 0; r < 64; ++r) {
        int row = w * 64 + r;
        float4 wv4 = *(const float4*)&Wv[row * 256 + lane * 4];
        float4 z4 = *(const float4*)&zl[lane * 4];
        float a = fmaf(z4.x, wv4.x, fmaf(z4.y, wv4.y, fmaf(z4.z, wv4.z, z4.w * wv4.w)));
        #pragma unroll
        for (int off = 32; off; off >>= 1) a += __shfl_down(a, off, 64);
        if (lane == 0)
            out[row] = ov[row] * (a + bv[row] * G) / den;
    }
}

extern "C" void kernel_launch(void* const* d_in, const int* in_sizes, int n_in,
                              void* d_out, int out_size, void* d_ws, size_t ws_size,
                              hipStream_t stream) {
    const float* x  = (const float*)d_in[0];
    const float* Wq = (const float*)d_in[1];  const float* bq = (const float*)d_in[2];
    const float* Wk = (const float*)d_in[3];  const float* bk = (const float*)d_in[4];
    const float* Wv = (const float*)d_in[5];  const float* bv = (const float*)d_in[6];
    const float* Wi = (const float*)d_in[7];  const float* bi = (const float*)d_in[8];
    const float* Wf = (const float*)d_in[9];  const float* bf = (const float*)d_in[10];
    const float* Wo = (const float*)d_in[11]; const float* bo = (const float*)d_in[12];
    const float* cw = (const float*)d_in[13]; const float* cb = (const float*)d_in[14];
    float* out = (float*)d_out;

    float* ws = (float*)d_ws;
    float* xpT = ws;                       // 256*2080 = 532480
    float* Wt  = xpT + 256 * TT;           // 3*256*384 = 294912
    float* zk  = Wt  + 3 * WTS;            // TP*H = 787584
    float* ai  = zk  + TP * H;             // TP*H
    float* lf  = ai  + TP * H;             // TP*H
    float* cs  = lf  + TP * H;             // NCS*H = 99840
    float* qv  = cs  + NCS * H;            // H
    float* ov  = qv  + H;                  // H
    float* zp  = ov  + H;                  // NC3*256 = 65792
    float* Gc  = zp  + NC3 * 256;          // 260
    int*   tk  = (int*)(Gc + 260);         // ticket

    p1_prep<<<808, 256, 0, stream>>>(x, cw, cb, Wk, Wi, Wf, Wq, bq, Wo, bo,
                                     xpT, Wt, qv, ov, tk);
    p2_gemm<<<dim3(MT, 9), 256, 0, stream>>>(xpT, Wt, bk, bi, bf, zk, ai, lf, cs);
    p3_tail<<<NC3, 384, 0, stream>>>(xpT, ai, lf, zk, cs, qv, ov, Wv, bv,
                                     zp, Gc, tk, out);
}